// Round 4
// baseline (427.245 us; speedup 1.0000x reference)
//
#include <hip/hip_runtime.h>
#include <hip/hip_bf16.h>

// EdgeBlock fused MLP:
//   out = relu(concat(edge, node[recv], node[send], g) @ W1 + b1) @ W2 + b2
// E=640000, N=10000, D=128, H=256, O=128.
//
// R4: BM=128 edges/block, 8 waves (512 thr), GEMM1 2M x 4N wave split.
//  - Halves per-edge W-fragment L2 traffic vs BM=64 (261 KB W re-read
//    amortized over 2x edges); gathers L1-dedup across N-split waves.
//  - Double-buffered (1-deep prefetch) weight fragments in both GEMM
//    K-loops: next-ks W loads issue before current MFMA cluster.
//  - launch_bounds(512,4): VGPR cap 128 (room for pipeline), 2 blocks/CU.
//  - Transposed MFMA (lane owns 4 consecutive feats of one edge) ->
//    cvt_pk epilogues, b64 LDS writes, dwordx4 stores.
//  - LDS 64 KiB: Xe (32 KiB, [128][128] bf16 swizzled) aliased under
//    Hs ([128][256] bf16 swizzled); Xe dead before epilogue1 writes.

typedef __attribute__((ext_vector_type(8))) short bf16x8;
typedef __attribute__((ext_vector_type(4))) float f32x4;
typedef __attribute__((ext_vector_type(2))) unsigned int u32x2;

static __device__ __forceinline__ unsigned short f2bf(float f) {
    unsigned u = __builtin_bit_cast(unsigned, f);
    u += 0x7FFFu + ((u >> 16) & 1u);   // round-to-nearest-even
    return (unsigned short)(u >> 16);
}

static __device__ __forceinline__ unsigned cvt_pk_bf16(float lo, float hi) {
    unsigned r;
    asm("v_cvt_pk_bf16_f32 %0, %1, %2" : "=v"(r) : "v"(lo), "v"(hi));
    return r;
}

// ---------------- prep kernels ----------------

// node_attr [10000][128] f32 -> bf16, 8 elems/thread
__global__ void prep_node_kernel(const float* __restrict__ node,
                                 ushort* __restrict__ nb) {
    int i = blockIdx.x * 256 + threadIdx.x;   // 0..159999
    if (i >= 160000) return;
    const float4* s = (const float4*)(node + (size_t)i * 8);
    float4 a = s[0], b = s[1];
    ushort tmp[8] = { f2bf(a.x), f2bf(a.y), f2bf(a.z), f2bf(a.w),
                      f2bf(b.x), f2bf(b.y), f2bf(b.z), f2bf(b.w) };
    *(bf16x8*)&nb[(size_t)i * 8] = *(bf16x8*)tmp;
}

// W1 [512][256] f32 (rows 0..383 used) -> fragment-packed bf16:
// block = gnt*12 + ks; lane l holds n = gnt*16 + (l&15), k = ks*32 + (l>>4)*8 + j.
__global__ void prep_w1_kernel(const float* __restrict__ W1,
                               ushort* __restrict__ w1f) {
    int id = blockIdx.x * 256 + threadIdx.x;  // 0..12287
    if (id >= 16 * 12 * 64) return;
    int l = id & 63, blk = id >> 6;
    int ks = blk % 12, gnt = blk / 12;
    int n  = gnt * 16 + (l & 15);
    int k0 = ks * 32 + (l >> 4) * 8;
    ushort tmp[8];
    #pragma unroll
    for (int j = 0; j < 8; ++j) tmp[j] = f2bf(W1[(k0 + j) * 256 + n]);
    *(bf16x8*)&w1f[(size_t)id * 8] = *(bf16x8*)tmp;
}

// W2 [256][128] f32 -> fragment-packed bf16 (8 n-tiles, 8 k-steps)
__global__ void prep_w2_kernel(const float* __restrict__ W2,
                               ushort* __restrict__ w2f) {
    int id = blockIdx.x * 256 + threadIdx.x;  // 0..4095
    if (id >= 8 * 8 * 64) return;
    int l = id & 63, blk = id >> 6;
    int ks = blk % 8, gnt = blk / 8;
    int n  = gnt * 16 + (l & 15);
    int k0 = ks * 32 + (l >> 4) * 8;
    ushort tmp[8];
    #pragma unroll
    for (int j = 0; j < 8; ++j) tmp[j] = f2bf(W2[(k0 + j) * 128 + n]);
    *(bf16x8*)&w2f[(size_t)id * 8] = *(bf16x8*)tmp;
}

// hbias[n] = b1[n] + sum_k g[k] * W1[384+k][n]   (fp32, exact global fold)
__global__ void prep_hbias_kernel(const float* __restrict__ W1,
                                  const float* __restrict__ b1,
                                  const float* __restrict__ g,
                                  float* __restrict__ hbias) {
    int n = threadIdx.x;  // 256 threads, 1 block
    float acc = b1[n];
    for (int k = 0; k < 128; ++k) acc += g[k] * W1[(384 + k) * 256 + n];
    hbias[n] = acc;
}

// ---------------- main fused kernel ----------------

__global__ __launch_bounds__(512, 4) void edge_mlp_kernel(
    const float* __restrict__ edge_attr,   // [E][128] f32
    const int* __restrict__ senders,
    const int* __restrict__ receivers,
    const ushort* __restrict__ node_bf,    // [N][128] bf16
    const ushort* __restrict__ w1f,        // frag-packed
    const ushort* __restrict__ w2f,        // frag-packed
    const float* __restrict__ hbias,       // [256]
    const float* __restrict__ b2,          // [128]
    float* __restrict__ out)               // [E][128] f32
{
    // 64 KiB shared, aliased: Xe = first 32 KiB ([128 edges][128 feats]),
    // Hs = full 64 KiB ([128 edges][256 feats]); both XOR-swizzled (8-elem
    // = 16B granule, 8-row period).
    __shared__ ushort Lds[128 * 256];
    ushort* Xe = Lds;
    ushort* Hs = Lds;

    const int t    = threadIdx.x;
    const int l    = t & 63;
    const int wid  = t >> 6;      // 0..7
    const int wm   = wid >> 2;    // 0..1 : edge-half
    const int wn   = wid & 3;     // 0..3 : feat-quarter
    const int base = blockIdx.x * 128;

    const int lr = l & 15;        // edge within 16-tile (MFMA col)
    const int q  = l >> 4;        // lane quarter
    const int lk = q * 8;         // MFMA k sub-offset within 32

    // per-lane gather row offsets for this wave's 4 edge-tiles
    int nrow[4], srow[4];
    #pragma unroll
    for (int mt = 0; mt < 4; ++mt) {
        int e = base + wm * 64 + mt * 16 + lr;
        nrow[mt] = receivers[e] * 128;
        srow[mt] = senders[e]   * 128;
    }

    // ---- stage edge segment: f32 -> bf16 into swizzled Xe (once/block) ----
    #pragma unroll
    for (int p = 0; p < 4; ++p) {
        int chunk = p * 512 + t;           // 0..2047: 128 rows x 16 chunks of 8
        int r  = chunk >> 4;
        int c0 = (chunk & 15) * 8;
        const float4* src = (const float4*)(edge_attr + (size_t)(base + r) * 128 + c0);
        float4 a = src[0];
        float4 b = src[1];
        uint4 uu = { cvt_pk_bf16(a.x, a.y), cvt_pk_bf16(a.z, a.w),
                     cvt_pk_bf16(b.x, b.y), cvt_pk_bf16(b.z, b.w) };
        *(bf16x8*)&Xe[r * 128 + (c0 ^ ((r & 7) << 3))] = __builtin_bit_cast(bf16x8, uu);
    }

    __syncthreads();

    // ---- GEMM1 (transposed): D row = hidden feat, col = edge ----
    f32x4 acc[4][4];  // [mt: edge-tile][nt: feat-tile]
    #pragma unroll
    for (int mt = 0; mt < 4; ++mt)
        #pragma unroll
        for (int nt = 0; nt < 4; ++nt)
            acc[mt][nt] = (f32x4){0.f, 0.f, 0.f, 0.f};

    // double-buffered W1 fragments: prefetch ks+1 before MFMAs of ks
    bf16x8 B[2][4];
    #pragma unroll
    for (int nt = 0; nt < 4; ++nt)
        B[0][nt] = *(const bf16x8*)&w1f[(size_t)(((wn * 4 + nt) * 12 + 0) * 64 + l) * 8];

    #pragma unroll
    for (int ks = 0; ks < 12; ++ks) {
        const int cur = ks & 1;
        if (ks < 11) {
            #pragma unroll
            for (int nt = 0; nt < 4; ++nt)
                B[cur ^ 1][nt] = *(const bf16x8*)&w1f[
                    (size_t)(((wn * 4 + nt) * 12 + (ks + 1)) * 64 + l) * 8];
        }
        bf16x8 X[4];
        if (ks < 4) {                        // edge segment from swizzled Xe
            const int kk = ks * 32 + lk;
            #pragma unroll
            for (int mt = 0; mt < 4; ++mt) {
                const int row = wm * 64 + mt * 16 + lr;
                X[mt] = *(const bf16x8*)&Xe[row * 128 + (kk ^ ((row & 7) << 3))];
            }
        } else {                             // node gathers (recv then send)
            const int off = (ks & 3) * 32 + lk;
            #pragma unroll
            for (int mt = 0; mt < 4; ++mt)
                X[mt] = *(const bf16x8*)&node_bf[(ks < 8 ? nrow[mt] : srow[mt]) + off];
        }
        #pragma unroll
        for (int mt = 0; mt < 4; ++mt)
            #pragma unroll
            for (int nt = 0; nt < 4; ++nt)
                acc[mt][nt] = __builtin_amdgcn_mfma_f32_16x16x32_bf16(
                    B[cur][nt], X[mt], acc[mt][nt], 0, 0, 0);
    }

    // all Xe reads (ks<4, all waves) complete before this barrier
    __syncthreads();

    // epilogue 1: +bias, relu, cvt_pk -> b64 swizzled Hs write
    #pragma unroll
    for (int nt = 0; nt < 4; ++nt) {
        const int F = wn * 64 + nt * 16 + q * 4;   // 4 consecutive feats
        float4 hb4 = *(const float4*)&hbias[F];
        #pragma unroll
        for (int mt = 0; mt < 4; ++mt) {
            float v0 = fmaxf(acc[mt][nt][0] + hb4.x, 0.f);
            float v1 = fmaxf(acc[mt][nt][1] + hb4.y, 0.f);
            float v2 = fmaxf(acc[mt][nt][2] + hb4.z, 0.f);
            float v3 = fmaxf(acc[mt][nt][3] + hb4.w, 0.f);
            u32x2 w = { cvt_pk_bf16(v0, v1), cvt_pk_bf16(v2, v3) };
            const int edge = wm * 64 + mt * 16 + lr;
            *(u32x2*)&Hs[edge * 256 + (F ^ ((edge & 7) << 3))] = w;
        }
    }

    __syncthreads();

    // ---- GEMM2 (transposed): D row = out feat, col = edge ----
    f32x4 acc2[4][2];  // [mt: edge-tile][nt: out-feat-tile]
    #pragma unroll
    for (int mt = 0; mt < 4; ++mt)
        #pragma unroll
        for (int nt = 0; nt < 2; ++nt)
            acc2[mt][nt] = (f32x4){0.f, 0.f, 0.f, 0.f};

    bf16x8 W2b[2][2];
    #pragma unroll
    for (int nt = 0; nt < 2; ++nt)
        W2b[0][nt] = *(const bf16x8*)&w2f[(size_t)(((wn * 2 + nt) * 8 + 0) * 64 + l) * 8];

    #pragma unroll
    for (int ks = 0; ks < 8; ++ks) {
        const int cur = ks & 1;
        if (ks < 7) {
            #pragma unroll
            for (int nt = 0; nt < 2; ++nt)
                W2b[cur ^ 1][nt] = *(const bf16x8*)&w2f[
                    (size_t)(((wn * 2 + nt) * 8 + (ks + 1)) * 64 + l) * 8];
        }
        bf16x8 Hfr[4];
        const int F = ks * 32 + lk;
        #pragma unroll
        for (int mt = 0; mt < 4; ++mt) {
            const int edge = wm * 64 + mt * 16 + lr;
            Hfr[mt] = *(const bf16x8*)&Hs[edge * 256 + (F ^ ((edge & 7) << 3))];
        }
        #pragma unroll
        for (int mt = 0; mt < 4; ++mt)
            #pragma unroll
            for (int nt = 0; nt < 2; ++nt)
                acc2[mt][nt] = __builtin_amdgcn_mfma_f32_16x16x32_bf16(
                    W2b[cur][nt], Hfr[mt], acc2[mt][nt], 0, 0, 0);
    }

    // epilogue 2: +b2, dwordx4 stores (4 consecutive out-feats per lane)
    #pragma unroll
    for (int nt = 0; nt < 2; ++nt) {
        const int F = wn * 32 + nt * 16 + q * 4;
        float4 b24 = *(const float4*)&b2[F];
        #pragma unroll
        for (int mt = 0; mt < 4; ++mt) {
            float4 o = { acc2[mt][nt][0] + b24.x, acc2[mt][nt][1] + b24.y,
                         acc2[mt][nt][2] + b24.z, acc2[mt][nt][3] + b24.w };
            *(float4*)&out[(size_t)(base + wm * 64 + mt * 16 + lr) * 128 + F] = o;
        }
    }
}

// ---------------- launcher ----------------

extern "C" void kernel_launch(void* const* d_in, const int* in_sizes, int n_in,
                              void* d_out, int out_size, void* d_ws, size_t ws_size,
                              hipStream_t stream) {
    (void)in_sizes; (void)n_in; (void)out_size; (void)ws_size;

    const float* edge_attr   = (const float*)d_in[0];  // [640000][128]
    const float* node_attr   = (const float*)d_in[1];  // [10000][128]
    const float* global_attr = (const float*)d_in[2];  // [128]
    const int*   senders     = (const int*)d_in[3];
    const int*   receivers   = (const int*)d_in[4];
    const float* W1          = (const float*)d_in[5];  // [512][256]
    const float* b1          = (const float*)d_in[6];  // [256]
    const float* W2          = (const float*)d_in[7];  // [256][128]
    const float* b2          = (const float*)d_in[8];  // [128]
    float* out = (float*)d_out;

    // workspace layout (all 16B aligned)
    ushort* node_bf = (ushort*)d_ws;                           // 2,560,000 B
    ushort* w1f     = (ushort*)((char*)d_ws + 2560000);        //   196,608 B
    ushort* w2f     = (ushort*)((char*)d_ws + 2756608);        //    65,536 B
    float*  hbias   = (float*)((char*)d_ws + 2822144);         //     1,024 B

    hipLaunchKernelGGL(prep_node_kernel,  dim3(625), dim3(256), 0, stream, node_attr, node_bf);
    hipLaunchKernelGGL(prep_w1_kernel,    dim3(48),  dim3(256), 0, stream, W1, w1f);
    hipLaunchKernelGGL(prep_w2_kernel,    dim3(16),  dim3(256), 0, stream, W2, w2f);
    hipLaunchKernelGGL(prep_hbias_kernel, dim3(1),   dim3(256), 0, stream, W1, b1, global_attr, hbias);

    hipLaunchKernelGGL(edge_mlp_kernel, dim3(5000), dim3(512), 0, stream,
                       edge_attr, senders, receivers, node_bf, w1f, w2f, hbias, b2, out);
}

// Round 5
// 312.641 us; speedup vs baseline: 1.3666x; 1.3666x over previous
//
#include <hip/hip_runtime.h>
#include <hip/hip_bf16.h>

// EdgeBlock fused MLP:
//   out = relu(concat(edge, node[recv], node[send], g) @ W1 + b1) @ W2 + b2
// E=640000, N=10000, D=128, H=256, O=128.
//
// R5: hoist node-dependent 2/3 of GEMM1 to per-NODE precompute (10000 rows
// vs 640000 edges):
//   Pr[n] = node[n] @ W1[128:256] + hbias   (bf16, 5 MB)
//   Ps[n] = node[n] @ W1[256:384]           (bf16, 5 MB)
//   h     = relu(edge @ W1[0:128] + Pr[recv] + Ps[send])
// Main kernel: BM=64, 4 waves, 2 barriers, Xe(16K)+Hs(32K) separate LDS.
// GEMM1' K=128 from LDS only; P rows gathered as 8B bf16x4 loads in the
// epilogue (independent loads, no MFMA chained on gathers).

typedef __attribute__((ext_vector_type(8))) short bf16x8;
typedef __attribute__((ext_vector_type(4))) float f32x4;
typedef __attribute__((ext_vector_type(2))) unsigned int u32x2;

static __device__ __forceinline__ unsigned short f2bf(float f) {
    unsigned u = __builtin_bit_cast(unsigned, f);
    u += 0x7FFFu + ((u >> 16) & 1u);   // round-to-nearest-even
    return (unsigned short)(u >> 16);
}

static __device__ __forceinline__ unsigned cvt_pk_bf16(float lo, float hi) {
    unsigned r;
    asm("v_cvt_pk_bf16_f32 %0, %1, %2" : "=v"(r) : "v"(lo), "v"(hi));
    return r;
}

// unpack packed-bf16 u32 (lo = [15:0], hi = [31:16]) to floats
static __device__ __forceinline__ float bflo(unsigned u) {
    return __builtin_bit_cast(float, u << 16);
}
static __device__ __forceinline__ float bfhi(unsigned u) {
    return __builtin_bit_cast(float, u & 0xFFFF0000u);
}

// ---------------- prep kernels ----------------

// W1 [512][256] f32 -> fragment-packed bf16:
// block = gnt*12 + ks; lane l holds n = gnt*16 + (l&15), k = ks*32 + (l>>4)*8 + j.
__global__ void prep_w1_kernel(const float* __restrict__ W1,
                               ushort* __restrict__ w1f) {
    int id = blockIdx.x * 256 + threadIdx.x;  // 0..12287
    if (id >= 16 * 12 * 64) return;
    int l = id & 63, blk = id >> 6;
    int ks = blk % 12, gnt = blk / 12;
    int n  = gnt * 16 + (l & 15);
    int k0 = ks * 32 + (l >> 4) * 8;
    ushort tmp[8];
    #pragma unroll
    for (int j = 0; j < 8; ++j) tmp[j] = f2bf(W1[(k0 + j) * 256 + n]);
    *(bf16x8*)&w1f[(size_t)id * 8] = *(bf16x8*)tmp;
}

// W2 [256][128] f32 -> fragment-packed bf16 (8 n-tiles, 8 k-steps)
__global__ void prep_w2_kernel(const float* __restrict__ W2,
                               ushort* __restrict__ w2f) {
    int id = blockIdx.x * 256 + threadIdx.x;  // 0..4095
    if (id >= 8 * 8 * 64) return;
    int l = id & 63, blk = id >> 6;
    int ks = blk % 8, gnt = blk / 8;
    int n  = gnt * 16 + (l & 15);
    int k0 = ks * 32 + (l >> 4) * 8;
    ushort tmp[8];
    #pragma unroll
    for (int j = 0; j < 8; ++j) tmp[j] = f2bf(W2[(k0 + j) * 128 + n]);
    *(bf16x8*)&w2f[(size_t)id * 8] = *(bf16x8*)tmp;
}

// hbias[n] = b1[n] + sum_k g[k] * W1[384+k][n]   (fp32, exact global fold)
__global__ void prep_hbias_kernel(const float* __restrict__ W1,
                                  const float* __restrict__ b1,
                                  const float* __restrict__ g,
                                  float* __restrict__ hbias) {
    int n = threadIdx.x;  // 256 threads, 1 block
    float acc = b1[n];
    for (int k = 0; k < 128; ++k) acc += g[k] * W1[(384 + k) * 256 + n];
    hbias[n] = acc;
}

// Per-node projections: Pr[n] = node[n] @ W1[128:256] + hbias,
//                       Ps[n] = node[n] @ W1[256:384].  64 nodes/block.
__global__ __launch_bounds__(256) void prep_proj_kernel(
    const float* __restrict__ node_attr,   // [10000][128] f32
    const ushort* __restrict__ w1f,        // frag-packed (uses ks 4..11)
    const float* __restrict__ hbias,       // [256]
    ushort* __restrict__ Pr,               // [10000][256] bf16
    ushort* __restrict__ Ps)               // [10000][256] bf16
{
    __shared__ ushort Xn[64 * 128];   // swizzled node rows, bf16

    const int t = threadIdx.x, l = t & 63, wn = t >> 6;
    const int base = blockIdx.x * 64;
    const int lr = l & 15, q = l >> 4, lk = q * 8;

    // stage 64 node rows f32 -> bf16 swizzled (clamped reads for tail block)
    #pragma unroll
    for (int p = 0; p < 4; ++p) {
        int chunk = p * 256 + t;
        int r  = chunk >> 4;
        int c0 = (chunk & 15) * 8;
        int node = base + r; if (node >= 10000) node = 9999;
        const float4* src = (const float4*)(node_attr + (size_t)node * 128 + c0);
        float4 a = src[0];
        float4 b = src[1];
        uint4 uu = { cvt_pk_bf16(a.x, a.y), cvt_pk_bf16(a.z, a.w),
                     cvt_pk_bf16(b.x, b.y), cvt_pk_bf16(b.z, b.w) };
        *(bf16x8*)&Xn[r * 128 + (c0 ^ ((r & 7) << 3))] = __builtin_bit_cast(bf16x8, uu);
    }
    __syncthreads();

    #pragma unroll
    for (int s = 0; s < 2; ++s) {
        f32x4 acc[4][4];
        #pragma unroll
        for (int mt = 0; mt < 4; ++mt)
            #pragma unroll
            for (int nt = 0; nt < 4; ++nt)
                acc[mt][nt] = (f32x4){0.f, 0.f, 0.f, 0.f};

        #pragma unroll
        for (int ks = 0; ks < 4; ++ks) {
            bf16x8 B[4];
            #pragma unroll
            for (int nt = 0; nt < 4; ++nt)
                B[nt] = *(const bf16x8*)&w1f[
                    (size_t)(((wn * 4 + nt) * 12 + 4 + s * 4 + ks) * 64 + l) * 8];
            bf16x8 X[4];
            const int kk = ks * 32 + lk;
            #pragma unroll
            for (int mt = 0; mt < 4; ++mt) {
                const int row = mt * 16 + lr;
                X[mt] = *(const bf16x8*)&Xn[row * 128 + (kk ^ ((row & 7) << 3))];
            }
            #pragma unroll
            for (int mt = 0; mt < 4; ++mt)
                #pragma unroll
                for (int nt = 0; nt < 4; ++nt)
                    acc[mt][nt] = __builtin_amdgcn_mfma_f32_16x16x32_bf16(
                        B[nt], X[mt], acc[mt][nt], 0, 0, 0);
        }

        ushort* P = s ? Ps : Pr;
        #pragma unroll
        for (int nt = 0; nt < 4; ++nt) {
            const int F = wn * 64 + nt * 16 + q * 4;
            float4 hb4 = {0.f, 0.f, 0.f, 0.f};
            if (s == 0) hb4 = *(const float4*)&hbias[F];
            #pragma unroll
            for (int mt = 0; mt < 4; ++mt) {
                const int node = base + mt * 16 + lr;
                if (node < 10000) {
                    u32x2 w = { cvt_pk_bf16(acc[mt][nt][0] + hb4.x,
                                            acc[mt][nt][1] + hb4.y),
                                cvt_pk_bf16(acc[mt][nt][2] + hb4.z,
                                            acc[mt][nt][3] + hb4.w) };
                    *(u32x2*)&P[(size_t)node * 256 + F] = w;
                }
            }
        }
    }
}

// ---------------- main fused kernel ----------------

__global__ __launch_bounds__(256, 3) void edge_mlp_kernel(
    const float* __restrict__ edge_attr,   // [E][128] f32
    const int* __restrict__ senders,
    const int* __restrict__ receivers,
    const ushort* __restrict__ w1f,        // frag-packed (uses ks 0..3)
    const ushort* __restrict__ w2f,        // frag-packed
    const ushort* __restrict__ Pr,         // [10000][256] bf16 (has hbias)
    const ushort* __restrict__ Ps,         // [10000][256] bf16
    const float* __restrict__ b2,          // [128]
    float* __restrict__ out)               // [E][128] f32
{
    __shared__ ushort Xe[64 * 128];   // 16 KiB, swizzled
    __shared__ ushort Hs[64 * 256];   // 32 KiB, swizzled

    const int t    = threadIdx.x;
    const int l    = t & 63;
    const int wid  = t >> 6;      // 0..3 : feat quarter
    const int base = blockIdx.x * 64;

    const int lr = l & 15;        // edge within 16-tile (MFMA col)
    const int q  = l >> 4;        // lane quarter
    const int lk = q * 8;         // MFMA k sub-offset within 32

    // per-lane P-row byte... element offsets for this wave's 4 edge-tiles
    int pr_off[4], ps_off[4];
    #pragma unroll
    for (int mt = 0; mt < 4; ++mt) {
        int e = base + mt * 16 + lr;
        pr_off[mt] = receivers[e] * 256;
        ps_off[mt] = senders[e]   * 256;
    }

    // ---- stage edge segment: f32 -> bf16 into swizzled Xe (once/block) ----
    #pragma unroll
    for (int p = 0; p < 4; ++p) {
        int chunk = p * 256 + t;           // 64 rows x 16 chunks of 8 floats
        int r  = chunk >> 4;
        int c0 = (chunk & 15) * 8;
        const float4* src = (const float4*)(edge_attr + (size_t)(base + r) * 128 + c0);
        float4 a = src[0];
        float4 b = src[1];
        uint4 uu = { cvt_pk_bf16(a.x, a.y), cvt_pk_bf16(a.z, a.w),
                     cvt_pk_bf16(b.x, b.y), cvt_pk_bf16(b.z, b.w) };
        *(bf16x8*)&Xe[r * 128 + (c0 ^ ((r & 7) << 3))] = __builtin_bit_cast(bf16x8, uu);
    }

    __syncthreads();

    // ---- GEMM1': D row = hidden feat, col = edge; K = 128 (edge seg only) --
    f32x4 acc[4][4];  // [mt: edge-tile][nt: feat-tile]
    #pragma unroll
    for (int mt = 0; mt < 4; ++mt)
        #pragma unroll
        for (int nt = 0; nt < 4; ++nt)
            acc[mt][nt] = (f32x4){0.f, 0.f, 0.f, 0.f};

    bf16x8 B[2][4];
    #pragma unroll
    for (int nt = 0; nt < 4; ++nt)
        B[0][nt] = *(const bf16x8*)&w1f[(size_t)(((wid * 4 + nt) * 12 + 0) * 64 + l) * 8];

    #pragma unroll
    for (int ks = 0; ks < 4; ++ks) {
        const int cur = ks & 1;
        if (ks < 3) {
            #pragma unroll
            for (int nt = 0; nt < 4; ++nt)
                B[cur ^ 1][nt] = *(const bf16x8*)&w1f[
                    (size_t)(((wid * 4 + nt) * 12 + (ks + 1)) * 64 + l) * 8];
        }
        bf16x8 X[4];
        const int kk = ks * 32 + lk;
        #pragma unroll
        for (int mt = 0; mt < 4; ++mt) {
            const int row = mt * 16 + lr;
            X[mt] = *(const bf16x8*)&Xe[row * 128 + (kk ^ ((row & 7) << 3))];
        }
        #pragma unroll
        for (int mt = 0; mt < 4; ++mt)
            #pragma unroll
            for (int nt = 0; nt < 4; ++nt)
                acc[mt][nt] = __builtin_amdgcn_mfma_f32_16x16x32_bf16(
                    B[cur][nt], X[mt], acc[mt][nt], 0, 0, 0);
    }

    // ---- P gathers: 32 independent 8B bf16x4 loads (no MFMA depends) ----
    u32x2 pg[4][4], sg[4][4];   // [nt][mt], fully unrolled -> registers
    #pragma unroll
    for (int nt = 0; nt < 4; ++nt) {
        const int F = wid * 64 + nt * 16 + q * 4;
        #pragma unroll
        for (int mt = 0; mt < 4; ++mt) {
            pg[nt][mt] = *(const u32x2*)&Pr[pr_off[mt] + F];
            sg[nt][mt] = *(const u32x2*)&Ps[ps_off[mt] + F];
        }
    }

    // epilogue 1: acc + Pr + Ps, relu, cvt_pk -> b64 swizzled Hs write
    #pragma unroll
    for (int nt = 0; nt < 4; ++nt) {
        const int F = wid * 64 + nt * 16 + q * 4;
        #pragma unroll
        for (int mt = 0; mt < 4; ++mt) {
            u32x2 p = pg[nt][mt], s = sg[nt][mt];
            float v0 = fmaxf(acc[mt][nt][0] + bflo(p.x) + bflo(s.x), 0.f);
            float v1 = fmaxf(acc[mt][nt][1] + bfhi(p.x) + bfhi(s.x), 0.f);
            float v2 = fmaxf(acc[mt][nt][2] + bflo(p.y) + bflo(s.y), 0.f);
            float v3 = fmaxf(acc[mt][nt][3] + bfhi(p.y) + bfhi(s.y), 0.f);
            u32x2 w = { cvt_pk_bf16(v0, v1), cvt_pk_bf16(v2, v3) };
            const int edge = mt * 16 + lr;
            *(u32x2*)&Hs[edge * 256 + (F ^ ((edge & 7) << 3))] = w;
        }
    }

    __syncthreads();

    // ---- GEMM2: D row = out feat, col = edge ----
    f32x4 acc2[4][2];  // [mt: edge-tile][nt: out-feat-tile]
    #pragma unroll
    for (int mt = 0; mt < 4; ++mt)
        #pragma unroll
        for (int nt = 0; nt < 2; ++nt)
            acc2[mt][nt] = (f32x4){0.f, 0.f, 0.f, 0.f};

    bf16x8 W2b[2][2];
    #pragma unroll
    for (int nt = 0; nt < 2; ++nt)
        W2b[0][nt] = *(const bf16x8*)&w2f[(size_t)(((wid * 2 + nt) * 8 + 0) * 64 + l) * 8];

    #pragma unroll
    for (int ks = 0; ks < 8; ++ks) {
        const int cur = ks & 1;
        if (ks < 7) {
            #pragma unroll
            for (int nt = 0; nt < 2; ++nt)
                W2b[cur ^ 1][nt] = *(const bf16x8*)&w2f[
                    (size_t)(((wid * 2 + nt) * 8 + (ks + 1)) * 64 + l) * 8];
        }
        bf16x8 Hfr[4];
        const int F = ks * 32 + lk;
        #pragma unroll
        for (int mt = 0; mt < 4; ++mt) {
            const int edge = mt * 16 + lr;
            Hfr[mt] = *(const bf16x8*)&Hs[edge * 256 + (F ^ ((edge & 7) << 3))];
        }
        #pragma unroll
        for (int mt = 0; mt < 4; ++mt)
            #pragma unroll
            for (int nt = 0; nt < 2; ++nt)
                acc2[mt][nt] = __builtin_amdgcn_mfma_f32_16x16x32_bf16(
                    W2b[cur][nt], Hfr[mt], acc2[mt][nt], 0, 0, 0);
    }

    // epilogue 2: +b2, dwordx4 stores (4 consecutive out-feats per lane)
    #pragma unroll
    for (int nt = 0; nt < 2; ++nt) {
        const int F = wid * 32 + nt * 16 + q * 4;
        float4 b24 = *(const float4*)&b2[F];
        #pragma unroll
        for (int mt = 0; mt < 4; ++mt) {
            float4 o = { acc2[mt][nt][0] + b24.x, acc2[mt][nt][1] + b24.y,
                         acc2[mt][nt][2] + b24.z, acc2[mt][nt][3] + b24.w };
            *(float4*)&out[(size_t)(base + mt * 16 + lr) * 128 + F] = o;
        }
    }
}

// ---------------- launcher ----------------

extern "C" void kernel_launch(void* const* d_in, const int* in_sizes, int n_in,
                              void* d_out, int out_size, void* d_ws, size_t ws_size,
                              hipStream_t stream) {
    (void)in_sizes; (void)n_in; (void)out_size; (void)ws_size;

    const float* edge_attr   = (const float*)d_in[0];  // [640000][128]
    const float* node_attr   = (const float*)d_in[1];  // [10000][128]
    const float* global_attr = (const float*)d_in[2];  // [128]
    const int*   senders     = (const int*)d_in[3];
    const int*   receivers   = (const int*)d_in[4];
    const float* W1          = (const float*)d_in[5];  // [512][256]
    const float* b1          = (const float*)d_in[6];  // [256]
    const float* W2          = (const float*)d_in[7];  // [256][128]
    const float* b2          = (const float*)d_in[8];  // [128]
    float* out = (float*)d_out;

    // workspace layout (all 16B aligned)
    ushort* w1f   = (ushort*)d_ws;                          //   196,608 B
    ushort* w2f   = (ushort*)((char*)d_ws + 196608);        //    65,536 B
    float*  hbias = (float*)((char*)d_ws + 262144);         //     1,024 B
    ushort* Pr    = (ushort*)((char*)d_ws + 263168);        // 5,120,000 B
    ushort* Ps    = (ushort*)((char*)d_ws + 5383168);       // 5,120,000 B
                                                            // total ~10.5 MB

    hipLaunchKernelGGL(prep_w1_kernel,    dim3(48),  dim3(256), 0, stream, W1, w1f);
    hipLaunchKernelGGL(prep_w2_kernel,    dim3(16),  dim3(256), 0, stream, W2, w2f);
    hipLaunchKernelGGL(prep_hbias_kernel, dim3(1),   dim3(256), 0, stream, W1, b1, global_attr, hbias);
    hipLaunchKernelGGL(prep_proj_kernel,  dim3(157), dim3(256), 0, stream,
                       node_attr, w1f, hbias, Pr, Ps);

    hipLaunchKernelGGL(edge_mlp_kernel, dim3(10000), dim3(256), 0, stream,
                       edge_attr, senders, receivers, w1f, w2f, Pr, Ps, b2, out);
}